// Round 1
// 278.876 us; speedup vs baseline: 1.0467x; 1.0467x over previous
//
#include <hip/hip_runtime.h>
#include <stdint.h>

// z: [16,1024,256] fp32 -> N=16384 rows, D=256
// embedding: [8192,256] fp32 -> K=8192 codes
// out = [ z_q (4194304 f32) | loss (1 f32) | indices (16384 as f32) ]
#define N_ROWS   16384
#define DIM      256
#define N_CODES  8192
#define ZQ_ELEMS 4194304

typedef _Float16 f16x8 __attribute__((ext_vector_type(8)));
typedef _Float16 f16x4 __attribute__((ext_vector_type(4)));
typedef float    f32x16 __attribute__((ext_vector_type(16)));
typedef unsigned long long u64;

// ---- workspace (bytes): et 8.65 MB | pkeys 256 KB ----
// etN layout in f16x8 units (16 B):
//   hi plane: (ksg*8192 + code)*2 + h   -> units 0..262143      (ksg 0..15, h=hi1 0..1)
//   lo plane: +262144                   -> units 262144..524287
//   aug:      524288 + code (||e||^2 hi/lo octet) | 532480 + code (zeros)
// ztN (lives in z_q output region, exactly 16 MB) in f16x8 units:
//   p*524288 + ksg*32768 + row*2 + h    (p=0 hi / 1 lo plane of -2z)
// Rationale (R11): pair-interleaving (ksg,h) makes the vq_main A-address
// SGPR-steppable (uniform base per ksg + loop-invariant lane voffset) and the
// B LDS address a single vaddr + 16-bit immediate -> near-zero inner-loop VALU.
#define WS_ET  0
#define WS_PK  (8650752)

static __device__ __forceinline__ void glds16(const void* gsrc, void* ldst) {
    __builtin_amdgcn_global_load_lds(
        (const __attribute__((address_space(1))) unsigned int*)gsrc,
        (__attribute__((address_space(3))) unsigned int*)ldst,
        16, 0, 0);
}

static __device__ __forceinline__ u64 packkey(float d, int c) {
    unsigned int u = __float_as_uint(d);
    u ^= ((unsigned int)((int)u >> 31)) | 0x80000000u;   // monotone float map
    return ((u64)u << 32) | (unsigned int)c;             // min => (dist, then idx)
}

// ---------------- fused prep: E (blocks 0..2047) + Z (blocks 2048..2559) ----------------
// LDS rows padded to 264 halves (528 B = 132 dw == 4 mod 32 banks): the read-out
// passes previously hit a 32-way bank conflict (all lanes at stride 512 B -> same
// bank quad); 264-stride gives uniform 8 lanes/quad = conflict-free b128 floor.
__global__ void vq_prep(const float* __restrict__ emb, const float* __restrict__ z,
                        _Float16* __restrict__ et, _Float16* __restrict__ zt,
                        float* __restrict__ loss_ptr) {
    __shared__ _Float16 shbuf[16896];            // 33 KB union, stride-264 rows
    const int t = threadIdx.x, w = t >> 6, l = t & 63;
    if (blockIdx.x < 2048) {
        if (blockIdx.x == 0 && t == 0) *loss_ptr = 0.0f;
        _Float16 (*lh)[264] = (_Float16(*)[264])shbuf;           // [4][264]
        _Float16 (*ll)[264] = (_Float16(*)[264])(shbuf + 1056);  // [4][264]
        const int code = blockIdx.x * 4 + w;
        float4 v = *(const float4*)(emb + (size_t)code * DIM + l * 4);
        float xs[4] = {v.x, v.y, v.z, v.w};
        f16x4 hh, lo;
        float s = 0.0f;
        #pragma unroll
        for (int i = 0; i < 4; ++i) {
            _Float16 h = (_Float16)xs[i];
            hh[i] = h;
            lo[i] = (_Float16)(xs[i] - (float)h);
            s += xs[i] * xs[i];
        }
        *(f16x4*)&lh[w][l * 4] = hh;
        *(f16x4*)&ll[w][l * 4] = lo;
        #pragma unroll
        for (int off = 32; off > 0; off >>= 1) s += __shfl_down(s, off, 64);
        if (l == 0) {                            // aug: ||e||^2 hi/lo + zeros
            _Float16 nh = (_Float16)s;
            _Float16 nl = (_Float16)(s - (float)nh);
            f16x8 aug, zr;
            #pragma unroll
            for (int i = 0; i < 8; ++i) { aug[i] = (_Float16)0; zr[i] = (_Float16)0; }
            aug[0] = nh; aug[1] = nl;
            *(f16x8*)(et + ((size_t)524288 + code) * 8) = aug;
            *(f16x8*)(et + ((size_t)532480 + code) * 8) = zr;
        }
        __syncthreads();
        const int p = t >> 7, g = t & 127;       // 2 planes x 4 codes x 32 octets
        const int cl = g & 3, fg = g >> 2;       // fg = dim-octet 0..31
        f16x8 frag = (p == 0) ? *(const f16x8*)&lh[cl][fg * 8]
                              : *(const f16x8*)&ll[cl][fg * 8];
        const size_t unit = (size_t)p * 262144 + (size_t)(fg >> 1) * 16384
                          + (size_t)(blockIdx.x * 4 + cl) * 2 + (fg & 1);
        *(f16x8*)(et + unit * 8) = frag;
    } else {
        _Float16 (*ls)[32][264] = (_Float16(*)[32][264])shbuf;   // [2][32][264]
        const int row0 = (blockIdx.x - 2048) * 32;
        #pragma unroll
        for (int j = 0; j < 8; ++j) {
            const int row = w * 8 + j;
            float4 v = *(const float4*)(z + (size_t)(row0 + row) * DIM + l * 4);
            float xs[4] = {v.x, v.y, v.z, v.w};
            f16x4 hh, lo;
            #pragma unroll
            for (int i = 0; i < 4; ++i) {
                const float m2 = -2.0f * xs[i];  // planes carry -2z
                _Float16 h = (_Float16)m2;
                hh[i] = h;
                lo[i] = (_Float16)(m2 - (float)h);
            }
            *(f16x4*)&ls[0][row][l * 4] = hh;
            *(f16x4*)&ls[1][row][l * 4] = lo;
        }
        __syncthreads();
        #pragma unroll
        for (int pp = 0; pp < 8; ++pp) {         // fully coalesced 1-KB unit-linear stores
            const int gi = pp * 256 + t;
            const int p = gi >> 10, rem = gi & 1023;
            const int ksg = rem >> 6, rr = rem & 63;
            const int row = rr >> 1, h = rr & 1;
            f16x8 frag = *(const f16x8*)&ls[p][row][(2 * ksg + h) * 8];
            const size_t unit = (size_t)p * 524288 + (size_t)ksg * 32768
                              + (size_t)(row0 + row) * 2 + h;
            *(f16x8*)(zt + unit * 8) = frag;
        }
    }
}

// ---------------- main: address-free inner loop, min-tree fold ----------------
// grid 256 = 128 row-blocks x 2 code-splits; 512 threads (8 waves, 2/SIMD, 1 blk/CU).
// A = e (global, L2-served, SGPR-stepped base + constant lane voffset + imm),
// B = z (-2z, LDS 128 KB persistent, one vaddr + 16-bit immediate per read).
// Aug-MFMA-first with C=0 initializes acc AND adds ||e||^2 (no accvgpr zero-init).
// Fold: f32 min-tree (31 v_min, AGPR-sourced) + equality index recovery + ONE
// packkey per nt (was 32 u64 packs). Register law: acc=128 AGPR, arch <=128.
__global__ __launch_bounds__(512, 2)
void vq_main(const _Float16* __restrict__ zt, const _Float16* __restrict__ et,
             u64* __restrict__ pkeys) {
    extern __shared__ char smem[];
    u64* run = (u64*)(smem + 131072);            // [8][128]

    const int tid = threadIdx.x;
    const int w = tid >> 6, L = tid & 63, lo5 = L & 31, hi1 = L >> 5;
    const int rb = blockIdx.x >> 1, sp = blockIdx.x & 1;  // sp is XCD-aligned (b%8 parity)
    const int row0 = rb * 128, codeS = sp * 4096;

    // ---- stage z once: 128 glds of 1 KB (16 per wave), LDS unit-linear ----
    // LDS unit (16 B) = ksg*256 + row*2 + h  (hi, bytes 0..65535); lo at +65536.
    #pragma unroll
    for (int i = 0; i < 16; ++i) {
        const int c = w * 16 + i;                // 0..127
        const int pl = c >> 6, cc = c & 63;
        glds16(zt + ((size_t)pl * 524288 + (size_t)(cc >> 2) * 32768
                     + (size_t)row0 * 2 + (cc & 3) * 64 + L) * 8,
               smem + ((c * 64 + L) << 4));
    }
    run[tid] = ~0ULL;
    run[tid + 512] = ~0ULL;
    __syncthreads();

    f16x8 bz;                                    // aug B: B[k0]=B[k1]=1 (hi1=0), else 0
    #pragma unroll
    for (int i = 0; i < 8; ++i) bz[i] = (_Float16)0;
    if (hi1 == 0) { bz[0] = (_Float16)1; bz[1] = (_Float16)1; }

    f32x16 zacc;                                 // constant C=0 for aug MFMAs
    #pragma unroll
    for (int e = 0; e < 16; ++e) zacc[e] = 0.0f;

    const f16x8* eb  = (const f16x8*)et;
    const f16x8* ebL = eb + 262144;              // lo plane
    const int laneU = lo5 * 2 + hi1;             // loop-invariant A voffset (units)
    const char* zbH = smem + (lo5 * 32 + hi1 * 16);
    const char* zbL = zbH + 65536;

    // prefetch aug-A for ci=0
    f16x8 paug[2];
    {
        const int c0 = codeS + w * 64;
        paug[0] = eb[(size_t)(64 + hi1) * 8192 + c0 + lo5];
        paug[1] = eb[(size_t)(64 + hi1) * 8192 + c0 + 32 + lo5];
    }

    for (int ci = 0; ci < 8; ++ci) {
        const int c0 = codeS + ci * 512 + w * 64;
        f32x16 acc[2][4];

        // aug-first: acc = ||e||^2 broadcast (also the zero-init)
        __builtin_amdgcn_s_setprio(1);
        #pragma unroll
        for (int mt = 0; mt < 2; ++mt)
            #pragma unroll
            for (int nt = 0; nt < 4; ++nt)
                acc[mt][nt] = __builtin_amdgcn_mfma_f32_32x32x16_f16(paug[mt], bz, zacc, 0, 0, 0);
        __builtin_amdgcn_s_setprio(0);

        if (ci < 7) {                            // prefetch aug-A for ci+1 (hides L2 lat)
            const int c1 = codeS + (ci + 1) * 512 + w * 64;
            paug[0] = eb[(size_t)(64 + hi1) * 8192 + c1 + lo5];
            paug[1] = eb[(size_t)(64 + hi1) * 8192 + c1 + 32 + lo5];
        }

        const size_t cu = (size_t)c0 * 2 + laneU;
        #pragma unroll 4
        for (int ksg = 0; ksg < 16; ++ksg) {
            const size_t ub = (size_t)ksg * 16384 + cu;
            f16x8 ah[2], al[2];
            ah[0] = eb[ub];       ah[1] = eb[ub + 64];
            al[0] = ebL[ub];      al[1] = ebL[ub + 64];
            f16x8 bh[4], bl[4];
            #pragma unroll
            for (int nt = 0; nt < 4; ++nt) {
                bh[nt] = *(const f16x8*)(zbH + (ksg * 4096 + nt * 1024));
                bl[nt] = *(const f16x8*)(zbL + (ksg * 4096 + nt * 1024));
            }
            __builtin_amdgcn_s_setprio(1);
            #pragma unroll
            for (int mt = 0; mt < 2; ++mt)
                #pragma unroll
                for (int nt = 0; nt < 4; ++nt) {
                    acc[mt][nt] = __builtin_amdgcn_mfma_f32_32x32x16_f16(ah[mt], bh[nt], acc[mt][nt], 0, 0, 0);
                    acc[mt][nt] = __builtin_amdgcn_mfma_f32_32x32x16_f16(ah[mt], bl[nt], acc[mt][nt], 0, 0, 0);
                    acc[mt][nt] = __builtin_amdgcn_mfma_f32_32x32x16_f16(al[mt], bh[nt], acc[mt][nt], 0, 0, 0);
                }
            __builtin_amdgcn_s_setprio(0);
        }

        // ---- fold: balanced f32 min-tree + first-match index, one packkey/nt ----
        #pragma unroll
        for (int nt = 0; nt < 4; ++nt) {
            float mm[16];
            #pragma unroll
            for (int r = 0; r < 16; ++r)
                mm[r] = fminf(acc[0][nt][r], acc[1][nt][r]);
            #pragma unroll
            for (int s2 = 8; s2 > 0; s2 >>= 1)
                #pragma unroll
                for (int r = 0; r < 8; ++r)
                    if (r < s2) mm[r] = fminf(mm[r], mm[r + s2]);
            const float m = mm[0];
            int rel = 64;                        // sentinel (inline const); rc max 59
            #pragma unroll
            for (int mt = 0; mt < 2; ++mt)
                #pragma unroll
                for (int r = 0; r < 16; ++r) {
                    const int rc = mt * 32 + (r & 3) + 8 * (r >> 2);
                    const int cand = (acc[mt][nt][r] == m) ? rc : 64;
                    rel = cand < rel ? cand : rel;   // monotone rc => lowest code wins
                }
            u64 best = packkey(m, c0 + 4 * hi1 + rel);
            const u64 o = __shfl_xor(best, 32, 64);  // merge code-halves (same row)
            if (o < best) best = o;
            if (hi1 == 0) {
                u64* p = &run[w * 128 + nt * 32 + lo5];  // sole writer per slot
                if (best < *p) *p = best;
            }
        }
    }

    __syncthreads();
    if (tid < 128) {
        u64 k = run[tid];
        #pragma unroll
        for (int w2 = 1; w2 < 8; ++w2) { u64 o = run[w2 * 128 + tid]; if (o < k) k = o; }
        pkeys[(size_t)sp * N_ROWS + row0 + tid] = k;
    }
}

// ---------------- final: merge 2 splits, idx, z_q gather, loss ----------------
__global__ __launch_bounds__(512)
void vq_final(const float* __restrict__ z, const float* __restrict__ emb,
              const u64* __restrict__ pkeys,
              float* __restrict__ zq_out, float* __restrict__ loss_out,
              float* __restrict__ idx_out) {
    __shared__ int best[64];
    const int t = threadIdx.x;
    const int row0 = blockIdx.x * 64;
    if (t < 64) {
        u64 k = pkeys[row0 + t];
        u64 o = pkeys[(size_t)N_ROWS + row0 + t];
        if (o < k) k = o;
        const int code = (int)(k & 0xFFFFFFFFu);
        best[t] = code;
        idx_out[row0 + t] = (float)code;
    }
    __syncthreads();
    const int wave = t >> 6, lane = t & 63;
    float lsum = 0.0f;
    #pragma unroll
    for (int rr = 0; rr < 8; ++rr) {
        const int rl = wave * 8 + rr;
        const int rg = row0 + rl;
        const int code = best[rl];
        float4 ev = *(const float4*)(emb + (size_t)code * DIM + lane * 4);
        float4 zv = *(const float4*)(z   + (size_t)rg   * DIM + lane * 4);
        float dx = ev.x - zv.x, dy = ev.y - zv.y;
        float dz = ev.z - zv.z, dw = ev.w - zv.w;
        lsum += dx * dx + dy * dy + dz * dz + dw * dw;
        *(float4*)(zq_out + (size_t)rg * DIM + lane * 4) = ev;
    }
    #pragma unroll
    for (int off = 32; off > 0; off >>= 1) lsum += __shfl_down(lsum, off, 64);
    if (lane == 0) atomicAdd(loss_out, lsum * (1.25f / (float)ZQ_ELEMS));
}

extern "C" void kernel_launch(void* const* d_in, const int* in_sizes, int n_in,
                              void* d_out, int out_size, void* d_ws, size_t ws_size,
                              hipStream_t stream) {
    const float* z   = (const float*)d_in[0];
    const float* emb = (const float*)d_in[1];
    float* out  = (float*)d_out;
    float* zq   = out;
    float* loss = out + ZQ_ELEMS;
    float* idx  = out + ZQ_ELEMS + 1;

    char* ws = (char*)d_ws;
    _Float16* et = (_Float16*)(ws + WS_ET);
    u64*   pk    = (u64*)(ws + WS_PK);

    // z tiled f16 planes (-2z) in the z_q output region (64 slabs * 16384 * 16 B)
    _Float16* zt = (_Float16*)zq;

    static bool attr_set = false;
    if (!attr_set) {
        hipFuncSetAttribute((const void*)vq_main,
                            hipFuncAttributeMaxDynamicSharedMemorySize, 139264);
        attr_set = true;
    }

    vq_prep<<<2560, 256, 0, stream>>>(emb, z, et, zt, loss);
    vq_main<<<256, 512, 139264, stream>>>(zt, et, pk);
    vq_final<<<N_ROWS / 64, 512, 0, stream>>>(z, emb, pk, zq, loss, idx);
}